// Round 9
// baseline (392.006 us; speedup 1.0000x reference)
//
#include <hip/hip_runtime.h>
#include <stdint.h>

typedef unsigned int u32;
typedef unsigned short u16;

#define NROWS 100000
#define DIM 512
#define HDIM 1024
#define OUTF 250
#define NSEG 256
#define LNEPS 1e-5f
#define BM 32
#define NG 3125            // 100000/32
#define PQ 8               // pool partial splits

typedef __bf16 bf16_t;
typedef bf16_t bf16x4 __attribute__((ext_vector_type(4)));
typedef bf16_t bf16x8 __attribute__((ext_vector_type(8)));
typedef float f32x4 __attribute__((ext_vector_type(4)));

__device__ inline int lower_bound(const int* __restrict__ a, int n, int v) {
    int lo = 0, hi = n;
    while (lo < hi) {
        int m = (lo + hi) >> 1;
        if (a[m] < v) lo = m + 1; else hi = m;
    }
    return lo;
}

// ---------------------------------------------------------------------------
// Kernel 0: convert gW1, mW1 ([1024][512]) and mW2 ([250->256 pad][1024])
// fp32 -> bf16 MFMA B-fragment order.
// Frag layout [ks][nt][lane] x 16B: n = nt*16+(lane&15), k = ks*32+(lane>>4)*8+j
// ---------------------------------------------------------------------------
__global__ __launch_bounds__(256) void k_conv(const float* __restrict__ gW1,
                                              const float* __restrict__ mW1,
                                              const float* __restrict__ mW2,
                                              u16* __restrict__ Wf,
                                              u16* __restrict__ mW1f,
                                              u16* __restrict__ mW2f) {
    int bid = blockIdx.x;
    if (bid < 512) {
        const float* src_base = (bid < 256) ? gW1 : mW1;
        u16* dst = (bid < 256) ? Wf : mW1f;
        int gid  = (bid & 255) * 256 + threadIdx.x;   // 0..65535
        int lane = gid & 63;
        int grp  = gid >> 6;                          // ks*64 + nt
        int ks   = grp >> 6, nt = grp & 63;
        int n    = nt * 16 + (lane & 15);
        int k0   = ks * 32 + ((lane >> 4) << 3);
        const float* src = src_base + (size_t)n * DIM + k0;
        float4 f0 = *reinterpret_cast<const float4*>(src);
        float4 f1 = *reinterpret_cast<const float4*>(src + 4);
        bf16x8 v;
        v[0] = (bf16_t)f0.x; v[1] = (bf16_t)f0.y;
        v[2] = (bf16_t)f0.z; v[3] = (bf16_t)f0.w;
        v[4] = (bf16_t)f1.x; v[5] = (bf16_t)f1.y;
        v[6] = (bf16_t)f1.z; v[7] = (bf16_t)f1.w;
        reinterpret_cast<bf16x8*>(dst)[gid] = v;
    } else {
        int gid  = (bid - 512) * 256 + threadIdx.x;   // 0..32767
        int lane = gid & 63;
        int grp  = gid >> 6;                          // ks*16 + nt
        int ks   = grp >> 4, nt = grp & 15;
        int n    = nt * 16 + (lane & 15);             // 0..255
        int k0   = ks * 32 + ((lane >> 4) << 3);
        bf16x8 v;
        if (n < OUTF) {
            const float* src = mW2 + (size_t)n * HDIM + k0;
            float4 f0 = *reinterpret_cast<const float4*>(src);
            float4 f1 = *reinterpret_cast<const float4*>(src + 4);
            v[0] = (bf16_t)f0.x; v[1] = (bf16_t)f0.y;
            v[2] = (bf16_t)f0.z; v[3] = (bf16_t)f0.w;
            v[4] = (bf16_t)f1.x; v[5] = (bf16_t)f1.y;
            v[6] = (bf16_t)f1.z; v[7] = (bf16_t)f1.w;
        } else {
            #pragma unroll
            for (int j = 0; j < 8; ++j) v[j] = (bf16_t)0.f;
        }
        reinterpret_cast<bf16x8*>(mW2f)[gid] = v;
    }
}

// ---------------------------------------------------------------------------
// Kernel 1: fused  gate[i] = relu(LN(x_i @ gW1.T + gb1)) . gW2 + gb2
// Round-4 proven structure: BM=32 (grid 3125), 8 waves, wave w owns cols
// [128w,128w+128); reg-staged LDS, pipelined K-loop. VGPR 60 + 64 AGPR.
// At this structure's plateau (~200us): L2 B-stream floor ~88us + HBM x
// ~32us + exposure; all BM=64 / persistent variants regressed (r2,3,5,7).
// ---------------------------------------------------------------------------
__global__ __launch_bounds__(512) void k_gate(
    const float* __restrict__ x, const u16* __restrict__ Wf,
    const float* __restrict__ gb1,
    const float* __restrict__ gln_g, const float* __restrict__ gln_b,
    const float* __restrict__ gW2, const float* __restrict__ gb2,
    float* __restrict__ gate)
{
    __shared__ __align__(16) u16 xlds[BM * DIM];   // 32KB, XOR-swizzled 16B units
    __shared__ float redS[8][BM];
    __shared__ float redQ[8][BM];
    __shared__ float meanA[BM], rstdA[BM];

    const int tid  = threadIdx.x;
    const int lane = tid & 63;
    const int w    = tid >> 6;          // wave 0..7
    const int l15  = lane & 15;
    const int g4   = lane >> 4;         // 0..3
    const int row0 = blockIdx.x * BM;

    // ---- stage x rows -> LDS bf16 (swizzled: unit u of row r at (u ^ (r&7)))
    #pragma unroll
    for (int uu = 0; uu < 4; ++uu) {
        int lu  = uu * 512 + tid;       // unit id 0..2047 (unit = 8 elements)
        int r   = lu >> 6;
        int u   = lu & 63;
        const float* src = x + (size_t)(row0 + r) * DIM + (u << 3);
        float4 f0 = *reinterpret_cast<const float4*>(src);
        float4 f1 = *reinterpret_cast<const float4*>(src + 4);
        bf16x8 v;
        v[0] = (bf16_t)f0.x; v[1] = (bf16_t)f0.y;
        v[2] = (bf16_t)f0.z; v[3] = (bf16_t)f0.w;
        v[4] = (bf16_t)f1.x; v[5] = (bf16_t)f1.y;
        v[6] = (bf16_t)f1.z; v[7] = (bf16_t)f1.w;
        int phys = r * DIM + ((u ^ (r & 7)) << 3);   // u16 units
        *reinterpret_cast<bf16x8*>(&xlds[phys]) = v;
    }
    __syncthreads();

    // ---- pipelined K loop
    f32x4 acc[2][8];
    #pragma unroll
    for (int m = 0; m < 2; ++m)
        #pragma unroll
        for (int t = 0; t < 8; ++t)
            acc[m][t] = (f32x4){0.f, 0.f, 0.f, 0.f};

    const bf16x8* __restrict__ WfB = reinterpret_cast<const bf16x8*>(Wf);

    auto loadB = [&](bf16x8 (&b)[8], int ks) {
        #pragma unroll
        for (int t = 0; t < 8; ++t)
            b[t] = WfB[(ks * 64 + w * 8 + t) * 64 + lane];
    };
    auto loadA = [&](bf16x8 (&a)[2], int ks) {
        #pragma unroll
        for (int m = 0; m < 2; ++m) {
            int r = m * 16 + l15;
            int u = ks * 4 + g4;
            a[m] = *reinterpret_cast<const bf16x8*>(&xlds[r * DIM + ((u ^ (r & 7)) << 3)]);
        }
    };
    auto domfma = [&](bf16x8 (&a)[2], bf16x8 (&b)[8]) {
        #pragma unroll
        for (int m = 0; m < 2; ++m)
            #pragma unroll
            for (int t = 0; t < 8; ++t)
                acc[m][t] = __builtin_amdgcn_mfma_f32_16x16x32_bf16(a[m], b[t], acc[m][t], 0, 0, 0);
    };

    bf16x8 b0[8], b1[8], a0[2], a1[2];
    loadB(b0, 0); loadA(a0, 0);
    #pragma unroll
    for (int ks2 = 0; ks2 < 8; ++ks2) {
        loadB(b1, 2 * ks2 + 1);
        loadA(a1, 2 * ks2 + 1);
        domfma(a0, b0);
        if (ks2 < 7) {
            loadB(b0, 2 * ks2 + 2);
            loadA(a0, 2 * ks2 + 2);
        }
        domfma(a1, b1);
    }

    // ---- bias add (affects LN stats)
    float cbias[8];
    #pragma unroll
    for (int t = 0; t < 8; ++t) cbias[t] = gb1[(w * 8 + t) * 16 + l15];
    #pragma unroll
    for (int m = 0; m < 2; ++m)
        #pragma unroll
        for (int t = 0; t < 8; ++t)
            #pragma unroll
            for (int j = 0; j < 4; ++j)
                acc[m][t][j] += cbias[t];

    // ---- per-row LN stats, streamed per row-slot
    #pragma unroll
    for (int m = 0; m < 2; ++m) {
        #pragma unroll
        for (int j = 0; j < 4; ++j) {
            float s1 = 0.f, s2 = 0.f;
            #pragma unroll
            for (int t = 0; t < 8; ++t) {
                float v = acc[m][t][j];
                s1 += v; s2 += v * v;
            }
            #pragma unroll
            for (int off = 1; off < 16; off <<= 1) {
                s1 += __shfl_xor(s1, off);
                s2 += __shfl_xor(s2, off);
            }
            if (l15 == 0) {
                int row = m * 16 + g4 * 4 + j;
                redS[w][row] = s1;
                redQ[w][row] = s2;
            }
        }
    }
    __syncthreads();
    if (tid < BM) {
        float S1 = 0.f, S2 = 0.f;
        #pragma unroll
        for (int ww = 0; ww < 8; ++ww) { S1 += redS[ww][tid]; S2 += redQ[ww][tid]; }
        float mean = S1 * (1.0f / 1024.0f);
        float var  = S2 * (1.0f / 1024.0f) - mean * mean;
        meanA[tid] = mean;
        rstdA[tid] = rsqrtf(var + LNEPS);
    }
    __syncthreads();

    // ---- LN + relu + dot(gW2), streamed per row-slot
    float cg[8], cb[8], cw[8];
    #pragma unroll
    for (int t = 0; t < 8; ++t) {
        int c = (w * 8 + t) * 16 + l15;
        cg[t] = gln_g[c]; cb[t] = gln_b[c]; cw[t] = gW2[c];
    }
    #pragma unroll
    for (int m = 0; m < 2; ++m) {
        #pragma unroll
        for (int j = 0; j < 4; ++j) {
            int row = m * 16 + g4 * 4 + j;
            float mn = meanA[row];
            float rs = rstdA[row];
            float gp = 0.f;
            #pragma unroll
            for (int t = 0; t < 8; ++t) {
                float h = (acc[m][t][j] - mn) * rs * cg[t] + cb[t];
                gp += fmaxf(h, 0.f) * cw[t];
            }
            #pragma unroll
            for (int off = 1; off < 16; off <<= 1)
                gp += __shfl_xor(gp, off);
            if (l15 == 0) redS[w][row] = gp;
        }
    }
    __syncthreads();
    if (tid < BM) {
        float s = gb2[0];
        #pragma unroll
        for (int ww = 0; ww < 8; ++ww) s += redS[ww][tid];
        gate[row0 + tid] = s;
    }
}

// ---------------------------------------------------------------------------
// Kernel 2: fused segment softmax + partial pooled sums.
// grid (NSEG, PQ) x 512 thr. pooledp[q][b][512].
// ---------------------------------------------------------------------------
__global__ __launch_bounds__(512) void k_poolseg(const int* __restrict__ ids,
                                                 const float* __restrict__ gate,
                                                 const float* __restrict__ x,
                                                 float* __restrict__ pooledp) {
    const int b = blockIdx.x, q = blockIdx.y, tid = threadIdx.x;
    const int start = lower_bound(ids, NROWS, b);
    const int end   = lower_bound(ids, NROWS, b + 1);

    __shared__ float red8[8];

    // ---- segment max
    float lm = -INFINITY;
    for (int i = start + tid; i < end; i += 512) lm = fmaxf(lm, gate[i]);
    #pragma unroll
    for (int off = 32; off; off >>= 1) lm = fmaxf(lm, __shfl_xor(lm, off));
    if ((tid & 63) == 0) red8[tid >> 6] = lm;
    __syncthreads();
    float m = red8[0];
    #pragma unroll
    for (int ww = 1; ww < 8; ++ww) m = fmaxf(m, red8[ww]);
    __syncthreads();

    // ---- segment sum(exp)
    float ls = 0.f;
    for (int i = start + tid; i < end; i += 512) ls += __expf(gate[i] - m);
    #pragma unroll
    for (int off = 32; off; off >>= 1) ls += __shfl_xor(ls, off);
    if ((tid & 63) == 0) red8[tid >> 6] = ls;
    __syncthreads();
    float den = 0.f;
    #pragma unroll
    for (int ww = 0; ww < 8; ++ww) den += red8[ww];
    const float inv = (den > 0.f) ? 1.0f / den : 0.0f;
    __syncthreads();

    // ---- partial pool
    const int slot   = tid & 127;     // f4 column slot
    const int stripe = tid >> 7;      // 0..3
    __shared__ f32x4 sh[4][128];      // 8 KB

    const f32x4* __restrict__ xr = reinterpret_cast<const f32x4*>(x);
    f32x4 acc = (f32x4){0.f, 0.f, 0.f, 0.f};
    for (int i = start + q * 4 + stripe; i < end; i += 4 * PQ) {
        float wgt = __expf(gate[i] - m) * inv;
        f32x4 xv = xr[(size_t)i * 128 + slot];
        acc += wgt * xv;
    }
    sh[stripe][slot] = acc;
    __syncthreads();
    if (tid < 128) {
        f32x4 r = sh[0][tid] + sh[1][tid] + sh[2][tid] + sh[3][tid];
        reinterpret_cast<f32x4*>(pooledp)[((size_t)q * NSEG + b) * 128 + tid] = r;
    }
}

// ---------------------------------------------------------------------------
// Kernel 3: y = LN_pn(sum_q pooledp) @ mW1.T + mb1   (MFMA, pln fused).
// grid (4 h-chunks, 2 seg-halves) x 512 thr. Each block sums the PQ pool
// partials for its 128 segs, applies pool-LN, converts to bf16 straight into
// its swizzled LDS A-tile (no outbf round-trip), then runs the K-loop.
// ---------------------------------------------------------------------------
__global__ __launch_bounds__(512) void k_heady(const float* __restrict__ pooledp,
                                               const float* __restrict__ pn_g,
                                               const float* __restrict__ pn_b,
                                               const u16* __restrict__ mW1f,
                                               const float* __restrict__ mb1,
                                               float* __restrict__ y) {
    __shared__ __align__(16) u16 alds[128 * DIM];   // 128KB
    const int tid  = threadIdx.x;
    const int lane = tid & 63;
    const int w    = tid >> 6;
    const int wm   = w >> 2;            // 0..1
    const int wn   = w & 3;             // 0..3
    const int l15  = lane & 15;
    const int g4   = lane >> 4;
    const int hc   = blockIdx.x;        // 0..3
    const int sh_  = blockIdx.y;        // 0..1

    // ---- fused pln: sum PQ partials + LN -> bf16 LDS A-tile
    {
        const int r   = tid >> 2;       // seg-local row 0..127
        const int c4  = tid & 3;        // 128-col quarter
        const int seg = sh_ * 128 + r;
        const f32x4* pp = reinterpret_cast<const f32x4*>(pooledp);
        // pass 1: stats over this thread's 128 cols
        float s = 0.f, qacc = 0.f;
        for (int cc = 0; cc < 32; ++cc) {
            f32x4 v = (f32x4){0.f, 0.f, 0.f, 0.f};
            #pragma unroll
            for (int qq = 0; qq < PQ; ++qq)
                v += pp[((size_t)qq * NSEG + seg) * 128 + c4 * 32 + cc];
            s    += v[0] + v[1] + v[2] + v[3];
            qacc += v[0]*v[0] + v[1]*v[1] + v[2]*v[2] + v[3]*v[3];
        }
        s += __shfl_xor(s, 1);    s += __shfl_xor(s, 2);
        qacc += __shfl_xor(qacc, 1); qacc += __shfl_xor(qacc, 2);
        float mean = s * (1.0f / 512.0f);
        float rstd = rsqrtf(qacc * (1.0f / 512.0f) - mean * mean + LNEPS);
        // pass 2: re-sum (L2-hot), apply LN, cvt, swizzled LDS store
        for (int cc = 0; cc < 16; ++cc) {
            int u = c4 * 16 + cc;       // 8-elem unit 0..63
            f32x4 v0 = (f32x4){0.f,0.f,0.f,0.f}, v1 = (f32x4){0.f,0.f,0.f,0.f};
            #pragma unroll
            for (int qq = 0; qq < PQ; ++qq) {
                v0 += pp[((size_t)qq * NSEG + seg) * 128 + u * 2];
                v1 += pp[((size_t)qq * NSEG + seg) * 128 + u * 2 + 1];
            }
            f32x4 g0 = reinterpret_cast<const f32x4*>(pn_g)[u * 2];
            f32x4 g1 = reinterpret_cast<const f32x4*>(pn_g)[u * 2 + 1];
            f32x4 bb0 = reinterpret_cast<const f32x4*>(pn_b)[u * 2];
            f32x4 bb1 = reinterpret_cast<const f32x4*>(pn_b)[u * 2 + 1];
            bf16x8 o;
            #pragma unroll
            for (int j = 0; j < 4; ++j) {
                o[j]     = (bf16_t)((v0[j] - mean) * rstd * g0[j] + bb0[j]);
                o[j + 4] = (bf16_t)((v1[j] - mean) * rstd * g1[j] + bb1[j]);
            }
            int phys = r * DIM + ((u ^ (r & 7)) << 3);
            *reinterpret_cast<bf16x8*>(&alds[phys]) = o;
        }
    }
    __syncthreads();

    f32x4 acc[4][4];
    #pragma unroll
    for (int m = 0; m < 4; ++m)
        #pragma unroll
        for (int t = 0; t < 4; ++t)
            acc[m][t] = (f32x4){0.f, 0.f, 0.f, 0.f};

    const bf16x8* __restrict__ WB = reinterpret_cast<const bf16x8*>(mW1f);
    #pragma unroll 4
    for (int ks = 0; ks < 16; ++ks) {
        bf16x8 b[4];
        #pragma unroll
        for (int t = 0; t < 4; ++t) {
            int nt_g = hc * 16 + wn * 4 + t;
            b[t] = WB[(ks * 64 + nt_g) * 64 + lane];
        }
        bf16x8 a[4];
        #pragma unroll
        for (int m = 0; m < 4; ++m) {
            int r = wm * 64 + m * 16 + l15;
            int u = ks * 4 + g4;
            a[m] = *reinterpret_cast<const bf16x8*>(&alds[r * DIM + ((u ^ (r & 7)) << 3)]);
        }
        #pragma unroll
        for (int m = 0; m < 4; ++m)
            #pragma unroll
            for (int t = 0; t < 4; ++t)
                acc[m][t] = __builtin_amdgcn_mfma_f32_16x16x32_bf16(a[m], b[t], acc[m][t], 0, 0, 0);
    }

    #pragma unroll
    for (int t = 0; t < 4; ++t) {
        int col = hc * 256 + (wn * 4 + t) * 16 + l15;
        float bias = mb1[col];
        #pragma unroll
        for (int m = 0; m < 4; ++m)
            #pragma unroll
            for (int j = 0; j < 4; ++j) {
                int seg = sh_ * 128 + wm * 64 + m * 16 + g4 * 4 + j;
                y[(size_t)seg * HDIM + col] = acc[m][t][j] + bias;
            }
    }
}

// ---------------------------------------------------------------------------
// Kernel 4: logits = relu(LN_mln(y)) @ mW2.T + mb2  (MFMA, headz fused).
// grid 2 (seg-halves) x 512 thr. Per-row LN stats pass over y, then LN+relu+
// cvt applied inline during each K-chunk's LDS staging.
// ---------------------------------------------------------------------------
__global__ __launch_bounds__(512) void k_logits(const float* __restrict__ y,
                                                const float* __restrict__ mln_g,
                                                const float* __restrict__ mln_b,
                                                const u16* __restrict__ mW2f,
                                                const float* __restrict__ mb2,
                                                float* __restrict__ logits) {
    __shared__ __align__(16) u16 alds[128 * 256];   // 64KB
    __shared__ float mnA[128], rsA[128];
    const int tid  = threadIdx.x;
    const int lane = tid & 63;
    const int w    = tid >> 6;
    const int wm   = w >> 2;
    const int wn   = w & 3;
    const int l15  = lane & 15;
    const int g4   = lane >> 4;
    const int sh_  = blockIdx.x;        // 0..1

    const f32x4* __restrict__ y4 = reinterpret_cast<const f32x4*>(y);

    // ---- fused headz stats: per-row mean/rstd over 1024 cols
    {
        const int r   = tid >> 2;       // 0..127
        const int c4  = tid & 3;        // 256-col quarter
        const int seg = sh_ * 128 + r;
        float s = 0.f, qacc = 0.f;
        for (int cc = 0; cc < 64; ++cc) {
            f32x4 v = y4[(size_t)seg * 256 + c4 * 64 + cc];
            s    += v[0] + v[1] + v[2] + v[3];
            qacc += v[0]*v[0] + v[1]*v[1] + v[2]*v[2] + v[3]*v[3];
        }
        s += __shfl_xor(s, 1);    s += __shfl_xor(s, 2);
        qacc += __shfl_xor(qacc, 1); qacc += __shfl_xor(qacc, 2);
        float mean = s * (1.0f / 1024.0f);
        mnA[r] = mean;
        rsA[r] = rsqrtf(qacc * (1.0f / 1024.0f) - mean * mean + LNEPS);
    }

    f32x4 acc[4][4];
    #pragma unroll
    for (int m = 0; m < 4; ++m)
        #pragma unroll
        for (int t = 0; t < 4; ++t)
            acc[m][t] = (f32x4){0.f, 0.f, 0.f, 0.f};

    const bf16x8* __restrict__ WB = reinterpret_cast<const bf16x8*>(mW2f);
    const f32x4* __restrict__ mg4 = reinterpret_cast<const f32x4*>(mln_g);
    const f32x4* __restrict__ mb4 = reinterpret_cast<const f32x4*>(mln_b);

    for (int kc = 0; kc < 4; ++kc) {
        __syncthreads();                 // kc=0: also publishes mnA/rsA
        #pragma unroll
        for (int uu = 0; uu < 8; ++uu) {
            int lu = uu * 512 + tid;    // 0..4095
            int r  = lu >> 5;           // 0..127
            int u  = lu & 31;           // unit within 256-col chunk
            float mean = mnA[r];
            float rstd = rsA[r];
            int f4i = kc * 64 + u * 2;  // f4 index within row
            f32x4 v0 = y4[(size_t)(sh_ * 128 + r) * 256 + f4i];
            f32x4 v1 = y4[(size_t)(sh_ * 128 + r) * 256 + f4i + 1];
            f32x4 g0 = mg4[f4i], g1 = mg4[f4i + 1];
            f32x4 bb0 = mb4[f4i], bb1 = mb4[f4i + 1];
            bf16x8 o;
            #pragma unroll
            for (int j = 0; j < 4; ++j) {
                o[j]     = (bf16_t)fmaxf((v0[j] - mean) * rstd * g0[j] + bb0[j], 0.f);
                o[j + 4] = (bf16_t)fmaxf((v1[j] - mean) * rstd * g1[j] + bb1[j], 0.f);
            }
            int phys = r * 256 + ((u ^ (r & 7)) << 3);
            *reinterpret_cast<bf16x8*>(&alds[phys]) = o;
        }
        __syncthreads();
        #pragma unroll
        for (int ksl = 0; ksl < 8; ++ksl) {
            bf16x8 b[4];
            #pragma unroll
            for (int t = 0; t < 4; ++t)
                b[t] = WB[((kc * 8 + ksl) * 16 + wn * 4 + t) * 64 + lane];
            bf16x8 a[4];
            #pragma unroll
            for (int m = 0; m < 4; ++m) {
                int r = wm * 64 + m * 16 + l15;
                int u = ksl * 4 + g4;
                a[m] = *reinterpret_cast<const bf16x8*>(&alds[r * 256 + ((u ^ (r & 7)) << 3)]);
            }
            #pragma unroll
            for (int m = 0; m < 4; ++m)
                #pragma unroll
                for (int t = 0; t < 4; ++t)
                    acc[m][t] = __builtin_amdgcn_mfma_f32_16x16x32_bf16(a[m], b[t], acc[m][t], 0, 0, 0);
        }
    }

    #pragma unroll
    for (int t = 0; t < 4; ++t) {
        int col = (wn * 4 + t) * 16 + l15;   // 0..255
        if (col < OUTF) {
            float bias = mb2[col];
            #pragma unroll
            for (int m = 0; m < 4; ++m)
                #pragma unroll
                for (int j = 0; j < 4; ++j) {
                    int seg = sh_ * 128 + wm * 64 + m * 16 + g4 * 4 + j;
                    logits[(size_t)seg * OUTF + col] = acc[m][t][j] + bias;
                }
        }
    }
}

// ---------------------------------------------------------------------------
extern "C" void kernel_launch(void* const* d_in, const int* in_sizes, int n_in,
                              void* d_out, int out_size, void* d_ws, size_t ws_size,
                              hipStream_t stream) {
    const float* x     = (const float*)d_in[0];
    const int*   ids   = (const int*)  d_in[1];
    const float* gW1   = (const float*)d_in[2];
    const float* gb1   = (const float*)d_in[3];
    const float* gln_g = (const float*)d_in[4];
    const float* gln_b = (const float*)d_in[5];
    const float* gW2   = (const float*)d_in[6];
    const float* gb2   = (const float*)d_in[7];
    const float* pn_g  = (const float*)d_in[8];
    const float* pn_b  = (const float*)d_in[9];
    const float* mW1   = (const float*)d_in[10];
    const float* mb1   = (const float*)d_in[11];
    const float* mln_g = (const float*)d_in[12];
    const float* mln_b = (const float*)d_in[13];
    const float* mW2   = (const float*)d_in[14];
    const float* mb2   = (const float*)d_in[15];
    float* logits = (float*)d_out;

    char* ws = (char*)d_ws;
    const size_t MB = 1 << 20;
    u16*   Wf      = (u16*)  (ws);                  // 1 MB
    u16*   mW1f    = (u16*)  (ws + 1 * MB);         // 1 MB
    u16*   mW2f    = (u16*)  (ws + 2 * MB);         // 512 KB
    float* gate    = (float*)(ws + 5 * MB / 2);     // 400 KB
    float* pooledp = (float*)(ws + 4 * MB);         // PQ*256*512*4 = 4 MB
    float* y       = (float*)(ws + 9 * MB);         // 1 MB

    hipLaunchKernelGGL(k_conv, dim3(640), dim3(256), 0, stream,
                       gW1, mW1, mW2, Wf, mW1f, mW2f);
    hipLaunchKernelGGL(k_gate, dim3(NG), dim3(512), 0, stream,
                       x, Wf, gb1, gln_g, gln_b, gW2, gb2, gate);
    hipLaunchKernelGGL(k_poolseg, dim3(NSEG, PQ), dim3(512), 0, stream,
                       ids, gate, x, pooledp);
    hipLaunchKernelGGL(k_heady, dim3(4, 2), dim3(512), 0, stream,
                       pooledp, pn_g, pn_b, mW1f, mb1, y);
    hipLaunchKernelGGL(k_logits, dim3(2), dim3(512), 0, stream,
                       y, mln_g, mln_b, mW2f, mb2, logits);
}

// Round 10
// 242.232 us; speedup vs baseline: 1.6183x; 1.6183x over previous
//
#include <hip/hip_runtime.h>
#include <stdint.h>

typedef unsigned int u32;
typedef unsigned short u16;

#define NROWS 100000
#define DIM 512
#define HDIM 1024
#define OUTF 250
#define NSEG 256
#define LNEPS 1e-5f
#define BM 32
#define NG 3125            // 100000/32
#define PQ 8               // pool partial splits

typedef __bf16 bf16_t;
typedef bf16_t bf16x4 __attribute__((ext_vector_type(4)));
typedef bf16_t bf16x8 __attribute__((ext_vector_type(8)));
typedef float f32x4 __attribute__((ext_vector_type(4)));

__device__ inline int lower_bound(const int* __restrict__ a, int n, int v) {
    int lo = 0, hi = n;
    while (lo < hi) {
        int m = (lo + hi) >> 1;
        if (a[m] < v) lo = m + 1; else hi = m;
    }
    return lo;
}

// ---------------------------------------------------------------------------
// Kernel 0: convert gW1, mW1 ([1024][512]) and mW2 ([250->256 pad][1024])
// fp32 -> bf16 MFMA B-fragment order.
// Frag layout [ks][nt][lane] x 16B: n = nt*16+(lane&15), k = ks*32+(lane>>4)*8+j
// ---------------------------------------------------------------------------
__global__ __launch_bounds__(256) void k_conv(const float* __restrict__ gW1,
                                              const float* __restrict__ mW1,
                                              const float* __restrict__ mW2,
                                              u16* __restrict__ Wf,
                                              u16* __restrict__ mW1f,
                                              u16* __restrict__ mW2f) {
    int bid = blockIdx.x;
    if (bid < 512) {
        const float* src_base = (bid < 256) ? gW1 : mW1;
        u16* dst = (bid < 256) ? Wf : mW1f;
        int gid  = (bid & 255) * 256 + threadIdx.x;   // 0..65535
        int lane = gid & 63;
        int grp  = gid >> 6;                          // ks*64 + nt
        int ks   = grp >> 6, nt = grp & 63;
        int n    = nt * 16 + (lane & 15);
        int k0   = ks * 32 + ((lane >> 4) << 3);
        const float* src = src_base + (size_t)n * DIM + k0;
        float4 f0 = *reinterpret_cast<const float4*>(src);
        float4 f1 = *reinterpret_cast<const float4*>(src + 4);
        bf16x8 v;
        v[0] = (bf16_t)f0.x; v[1] = (bf16_t)f0.y;
        v[2] = (bf16_t)f0.z; v[3] = (bf16_t)f0.w;
        v[4] = (bf16_t)f1.x; v[5] = (bf16_t)f1.y;
        v[6] = (bf16_t)f1.z; v[7] = (bf16_t)f1.w;
        reinterpret_cast<bf16x8*>(dst)[gid] = v;
    } else {
        int gid  = (bid - 512) * 256 + threadIdx.x;   // 0..32767
        int lane = gid & 63;
        int grp  = gid >> 6;                          // ks*16 + nt
        int ks   = grp >> 4, nt = grp & 15;
        int n    = nt * 16 + (lane & 15);             // 0..255
        int k0   = ks * 32 + ((lane >> 4) << 3);
        bf16x8 v;
        if (n < OUTF) {
            const float* src = mW2 + (size_t)n * HDIM + k0;
            float4 f0 = *reinterpret_cast<const float4*>(src);
            float4 f1 = *reinterpret_cast<const float4*>(src + 4);
            v[0] = (bf16_t)f0.x; v[1] = (bf16_t)f0.y;
            v[2] = (bf16_t)f0.z; v[3] = (bf16_t)f0.w;
            v[4] = (bf16_t)f1.x; v[5] = (bf16_t)f1.y;
            v[6] = (bf16_t)f1.z; v[7] = (bf16_t)f1.w;
        } else {
            #pragma unroll
            for (int j = 0; j < 8; ++j) v[j] = (bf16_t)0.f;
        }
        reinterpret_cast<bf16x8*>(mW2f)[gid] = v;
    }
}

// ---------------------------------------------------------------------------
// Kernel 1: fused  gate[i] = relu(LN(x_i @ gW1.T + gb1)) . gW2 + gb2
// Round-4 proven structure: BM=32 (grid 3125), 8 waves, wave w owns cols
// [128w,128w+128); reg-staged LDS, pipelined K-loop. VGPR 60 + 64 AGPR.
// Structure plateau ~200us: L2 B-stream floor ~88us + HBM x ~32us + latency
// exposure. BM=64 variants and persistent/gload_lds variants all regressed
// (r2,r3,r5,r7: spill or occupancy/convoy loss). Do not restructure casually.
// ---------------------------------------------------------------------------
__global__ __launch_bounds__(512) void k_gate(
    const float* __restrict__ x, const u16* __restrict__ Wf,
    const float* __restrict__ gb1,
    const float* __restrict__ gln_g, const float* __restrict__ gln_b,
    const float* __restrict__ gW2, const float* __restrict__ gb2,
    float* __restrict__ gate)
{
    __shared__ __align__(16) u16 xlds[BM * DIM];   // 32KB, XOR-swizzled 16B units
    __shared__ float redS[8][BM];
    __shared__ float redQ[8][BM];
    __shared__ float meanA[BM], rstdA[BM];

    const int tid  = threadIdx.x;
    const int lane = tid & 63;
    const int w    = tid >> 6;          // wave 0..7
    const int l15  = lane & 15;
    const int g4   = lane >> 4;         // 0..3
    const int row0 = blockIdx.x * BM;

    // ---- stage x rows -> LDS bf16 (swizzled: unit u of row r at (u ^ (r&7)))
    #pragma unroll
    for (int uu = 0; uu < 4; ++uu) {
        int lu  = uu * 512 + tid;       // unit id 0..2047 (unit = 8 elements)
        int r   = lu >> 6;
        int u   = lu & 63;
        const float* src = x + (size_t)(row0 + r) * DIM + (u << 3);
        float4 f0 = *reinterpret_cast<const float4*>(src);
        float4 f1 = *reinterpret_cast<const float4*>(src + 4);
        bf16x8 v;
        v[0] = (bf16_t)f0.x; v[1] = (bf16_t)f0.y;
        v[2] = (bf16_t)f0.z; v[3] = (bf16_t)f0.w;
        v[4] = (bf16_t)f1.x; v[5] = (bf16_t)f1.y;
        v[6] = (bf16_t)f1.z; v[7] = (bf16_t)f1.w;
        int phys = r * DIM + ((u ^ (r & 7)) << 3);   // u16 units
        *reinterpret_cast<bf16x8*>(&xlds[phys]) = v;
    }
    __syncthreads();

    // ---- pipelined K loop
    f32x4 acc[2][8];
    #pragma unroll
    for (int m = 0; m < 2; ++m)
        #pragma unroll
        for (int t = 0; t < 8; ++t)
            acc[m][t] = (f32x4){0.f, 0.f, 0.f, 0.f};

    const bf16x8* __restrict__ WfB = reinterpret_cast<const bf16x8*>(Wf);

    auto loadB = [&](bf16x8 (&b)[8], int ks) {
        #pragma unroll
        for (int t = 0; t < 8; ++t)
            b[t] = WfB[(ks * 64 + w * 8 + t) * 64 + lane];
    };
    auto loadA = [&](bf16x8 (&a)[2], int ks) {
        #pragma unroll
        for (int m = 0; m < 2; ++m) {
            int r = m * 16 + l15;
            int u = ks * 4 + g4;
            a[m] = *reinterpret_cast<const bf16x8*>(&xlds[r * DIM + ((u ^ (r & 7)) << 3)]);
        }
    };
    auto domfma = [&](bf16x8 (&a)[2], bf16x8 (&b)[8]) {
        #pragma unroll
        for (int m = 0; m < 2; ++m)
            #pragma unroll
            for (int t = 0; t < 8; ++t)
                acc[m][t] = __builtin_amdgcn_mfma_f32_16x16x32_bf16(a[m], b[t], acc[m][t], 0, 0, 0);
    };

    bf16x8 b0[8], b1[8], a0[2], a1[2];
    loadB(b0, 0); loadA(a0, 0);
    #pragma unroll
    for (int ks2 = 0; ks2 < 8; ++ks2) {
        loadB(b1, 2 * ks2 + 1);
        loadA(a1, 2 * ks2 + 1);
        domfma(a0, b0);
        if (ks2 < 7) {
            loadB(b0, 2 * ks2 + 2);
            loadA(a0, 2 * ks2 + 2);
        }
        domfma(a1, b1);
    }

    // ---- bias add (affects LN stats)
    float cbias[8];
    #pragma unroll
    for (int t = 0; t < 8; ++t) cbias[t] = gb1[(w * 8 + t) * 16 + l15];
    #pragma unroll
    for (int m = 0; m < 2; ++m)
        #pragma unroll
        for (int t = 0; t < 8; ++t)
            #pragma unroll
            for (int j = 0; j < 4; ++j)
                acc[m][t][j] += cbias[t];

    // ---- per-row LN stats, streamed per row-slot
    #pragma unroll
    for (int m = 0; m < 2; ++m) {
        #pragma unroll
        for (int j = 0; j < 4; ++j) {
            float s1 = 0.f, s2 = 0.f;
            #pragma unroll
            for (int t = 0; t < 8; ++t) {
                float v = acc[m][t][j];
                s1 += v; s2 += v * v;
            }
            #pragma unroll
            for (int off = 1; off < 16; off <<= 1) {
                s1 += __shfl_xor(s1, off);
                s2 += __shfl_xor(s2, off);
            }
            if (l15 == 0) {
                int row = m * 16 + g4 * 4 + j;
                redS[w][row] = s1;
                redQ[w][row] = s2;
            }
        }
    }
    __syncthreads();
    if (tid < BM) {
        float S1 = 0.f, S2 = 0.f;
        #pragma unroll
        for (int ww = 0; ww < 8; ++ww) { S1 += redS[ww][tid]; S2 += redQ[ww][tid]; }
        float mean = S1 * (1.0f / 1024.0f);
        float var  = S2 * (1.0f / 1024.0f) - mean * mean;
        meanA[tid] = mean;
        rstdA[tid] = rsqrtf(var + LNEPS);
    }
    __syncthreads();

    // ---- LN + relu + dot(gW2), streamed per row-slot
    float cg[8], cb[8], cw[8];
    #pragma unroll
    for (int t = 0; t < 8; ++t) {
        int c = (w * 8 + t) * 16 + l15;
        cg[t] = gln_g[c]; cb[t] = gln_b[c]; cw[t] = gW2[c];
    }
    #pragma unroll
    for (int m = 0; m < 2; ++m) {
        #pragma unroll
        for (int j = 0; j < 4; ++j) {
            int row = m * 16 + g4 * 4 + j;
            float mn = meanA[row];
            float rs = rstdA[row];
            float gp = 0.f;
            #pragma unroll
            for (int t = 0; t < 8; ++t) {
                float h = (acc[m][t][j] - mn) * rs * cg[t] + cb[t];
                gp += fmaxf(h, 0.f) * cw[t];
            }
            #pragma unroll
            for (int off = 1; off < 16; off <<= 1)
                gp += __shfl_xor(gp, off);
            if (l15 == 0) redS[w][row] = gp;
        }
    }
    __syncthreads();
    if (tid < BM) {
        float s = gb2[0];
        #pragma unroll
        for (int ww = 0; ww < 8; ++ww) s += redS[ww][tid];
        gate[row0 + tid] = s;
    }
}

// ---------------------------------------------------------------------------
// Kernel 2: fused segment softmax + partial pooled sums.
// grid (NSEG, PQ) x 512 thr. Each block recomputes its segment's max/denom
// (gate is L2-resident), then partial weighted x-sums. pooledp[q][b][512].
// Wide grid (2048 blocks) keeps the x-read at its ~33us HBM floor.
// ---------------------------------------------------------------------------
__global__ __launch_bounds__(512) void k_poolseg(const int* __restrict__ ids,
                                                 const float* __restrict__ gate,
                                                 const float* __restrict__ x,
                                                 float* __restrict__ pooledp) {
    const int b = blockIdx.x, q = blockIdx.y, tid = threadIdx.x;
    const int start = lower_bound(ids, NROWS, b);
    const int end   = lower_bound(ids, NROWS, b + 1);

    __shared__ float red8[8];

    // ---- segment max
    float lm = -INFINITY;
    for (int i = start + tid; i < end; i += 512) lm = fmaxf(lm, gate[i]);
    #pragma unroll
    for (int off = 32; off; off >>= 1) lm = fmaxf(lm, __shfl_xor(lm, off));
    if ((tid & 63) == 0) red8[tid >> 6] = lm;
    __syncthreads();
    float m = red8[0];
    #pragma unroll
    for (int ww = 1; ww < 8; ++ww) m = fmaxf(m, red8[ww]);
    __syncthreads();

    // ---- segment sum(exp)
    float ls = 0.f;
    for (int i = start + tid; i < end; i += 512) ls += __expf(gate[i] - m);
    #pragma unroll
    for (int off = 32; off; off >>= 1) ls += __shfl_xor(ls, off);
    if ((tid & 63) == 0) red8[tid >> 6] = ls;
    __syncthreads();
    float den = 0.f;
    #pragma unroll
    for (int ww = 0; ww < 8; ++ww) den += red8[ww];
    const float inv = (den > 0.f) ? 1.0f / den : 0.0f;
    __syncthreads();

    // ---- partial pool
    const int slot   = tid & 127;     // f4 column slot
    const int stripe = tid >> 7;      // 0..3
    __shared__ f32x4 sh[4][128];      // 8 KB

    const f32x4* __restrict__ xr = reinterpret_cast<const f32x4*>(x);
    f32x4 acc = (f32x4){0.f, 0.f, 0.f, 0.f};
    for (int i = start + q * 4 + stripe; i < end; i += 4 * PQ) {
        float wgt = __expf(gate[i] - m) * inv;
        f32x4 xv = xr[(size_t)i * 128 + slot];
        acc += wgt * xv;
    }
    sh[stripe][slot] = acc;
    __syncthreads();
    if (tid < 128) {
        f32x4 r = sh[0][tid] + sh[1][tid] + sh[2][tid] + sh[3][tid];
        reinterpret_cast<f32x4*>(pooledp)[((size_t)q * NSEG + b) * 128 + tid] = r;
    }
}

// ---------------------------------------------------------------------------
// Kernel 3: sum PQ partials + LN(pn) -> outbf [256][512] bf16 row-major
// (kept as separate 256-block kernel: r9 fusion into 8-block k_heady
//  serialized this pass and cost +150us)
// ---------------------------------------------------------------------------
__global__ __launch_bounds__(128) void k_pln(const float* __restrict__ pooledp,
                                             const float* __restrict__ pn_g,
                                             const float* __restrict__ pn_b,
                                             u16* __restrict__ outbf) {
    const int b = blockIdx.x, tid = threadIdx.x;   // 128 threads, 2 waves
    const f32x4* pp = reinterpret_cast<const f32x4*>(pooledp);
    f32x4 v = (f32x4){0.f, 0.f, 0.f, 0.f};
    #pragma unroll
    for (int qq = 0; qq < PQ; ++qq)
        v += pp[((size_t)qq * NSEG + b) * 128 + tid];
    float s = v[0] + v[1] + v[2] + v[3];
    float q = v[0]*v[0] + v[1]*v[1] + v[2]*v[2] + v[3]*v[3];
    #pragma unroll
    for (int off = 32; off; off >>= 1) {
        s += __shfl_xor(s, off);
        q += __shfl_xor(q, off);
    }
    __shared__ float sh[4];
    if ((tid & 63) == 0) { sh[(tid >> 6) * 2] = s; sh[(tid >> 6) * 2 + 1] = q; }
    __syncthreads();
    float S = sh[0] + sh[2], Q = sh[1] + sh[3];
    float mean = S * (1.0f / 512.0f);
    float rstd = rsqrtf(Q * (1.0f / 512.0f) - mean * mean + LNEPS);
    f32x4 g = reinterpret_cast<const f32x4*>(pn_g)[tid];
    f32x4 bb = reinterpret_cast<const f32x4*>(pn_b)[tid];
    bf16x4 o;
    #pragma unroll
    for (int j = 0; j < 4; ++j)
        o[j] = (bf16_t)((v[j] - mean) * rstd * g[j] + bb[j]);
    reinterpret_cast<bf16x4*>(outbf)[b * 128 + tid] = o;
}

// ---------------------------------------------------------------------------
// Kernel 4: y = outbf @ mW1.T + mb1   (MFMA).  grid (4 h-chunks, 2 seg-halves)
// ---------------------------------------------------------------------------
__global__ __launch_bounds__(512) void k_heady(const u16* __restrict__ outbf,
                                               const u16* __restrict__ mW1f,
                                               const float* __restrict__ mb1,
                                               float* __restrict__ y) {
    __shared__ __align__(16) u16 alds[128 * DIM];   // 128KB
    const int tid  = threadIdx.x;
    const int lane = tid & 63;
    const int w    = tid >> 6;
    const int wm   = w >> 2;            // 0..1
    const int wn   = w & 3;             // 0..3
    const int l15  = lane & 15;
    const int g4   = lane >> 4;
    const int hc   = blockIdx.x;        // 0..3
    const int sh_  = blockIdx.y;        // 0..1

    const uint4* srcU = reinterpret_cast<const uint4*>(outbf);
    #pragma unroll
    for (int uu = 0; uu < 16; ++uu) {
        int lu = uu * 512 + tid;        // 0..8191
        int r  = lu >> 6;               // 0..127
        int u  = lu & 63;
        uint4 val = srcU[(size_t)(sh_ * 128 + r) * 64 + u];
        int phys = r * DIM + ((u ^ (r & 7)) << 3);
        *reinterpret_cast<uint4*>(&alds[phys]) = val;
    }
    __syncthreads();

    f32x4 acc[4][4];
    #pragma unroll
    for (int m = 0; m < 4; ++m)
        #pragma unroll
        for (int t = 0; t < 4; ++t)
            acc[m][t] = (f32x4){0.f, 0.f, 0.f, 0.f};

    const bf16x8* __restrict__ WB = reinterpret_cast<const bf16x8*>(mW1f);
    #pragma unroll 4
    for (int ks = 0; ks < 16; ++ks) {
        bf16x8 b[4];
        #pragma unroll
        for (int t = 0; t < 4; ++t) {
            int nt_g = hc * 16 + wn * 4 + t;
            b[t] = WB[(ks * 64 + nt_g) * 64 + lane];
        }
        bf16x8 a[4];
        #pragma unroll
        for (int m = 0; m < 4; ++m) {
            int r = wm * 64 + m * 16 + l15;
            int u = ks * 4 + g4;
            a[m] = *reinterpret_cast<const bf16x8*>(&alds[r * DIM + ((u ^ (r & 7)) << 3)]);
        }
        #pragma unroll
        for (int m = 0; m < 4; ++m)
            #pragma unroll
            for (int t = 0; t < 4; ++t)
                acc[m][t] = __builtin_amdgcn_mfma_f32_16x16x32_bf16(a[m], b[t], acc[m][t], 0, 0, 0);
    }

    #pragma unroll
    for (int t = 0; t < 4; ++t) {
        int col = hc * 256 + (wn * 4 + t) * 16 + l15;
        float bias = mb1[col];
        #pragma unroll
        for (int m = 0; m < 4; ++m)
            #pragma unroll
            for (int j = 0; j < 4; ++j) {
                int seg = sh_ * 128 + wm * 64 + m * 16 + g4 * 4 + j;
                y[(size_t)seg * HDIM + col] = acc[m][t][j] + bias;
            }
    }
}

// ---------------------------------------------------------------------------
// Kernel 5: z = relu(LN(y)*mln_g+mln_b) -> zbf [256][1024] bf16
// (kept as separate 256-block kernel — see r9 lesson)
// ---------------------------------------------------------------------------
__global__ __launch_bounds__(256) void k_headz(const float* __restrict__ y,
                                               const float* __restrict__ mln_g,
                                               const float* __restrict__ mln_b,
                                               u16* __restrict__ zbf) {
    const int b = blockIdx.x, tid = threadIdx.x;   // 256 threads, 4 waves
    f32x4 v = reinterpret_cast<const f32x4*>(y)[b * 256 + tid];
    float s = v[0] + v[1] + v[2] + v[3];
    float q = v[0]*v[0] + v[1]*v[1] + v[2]*v[2] + v[3]*v[3];
    #pragma unroll
    for (int off = 32; off; off >>= 1) {
        s += __shfl_xor(s, off);
        q += __shfl_xor(q, off);
    }
    __shared__ float sh[8];
    if ((tid & 63) == 0) { sh[(tid >> 6) * 2] = s; sh[(tid >> 6) * 2 + 1] = q; }
    __syncthreads();
    float S = sh[0] + sh[2] + sh[4] + sh[6];
    float Q = sh[1] + sh[3] + sh[5] + sh[7];
    float mean = S * (1.0f / 1024.0f);
    float rstd = rsqrtf(Q * (1.0f / 1024.0f) - mean * mean + LNEPS);
    f32x4 g = reinterpret_cast<const f32x4*>(mln_g)[tid];
    f32x4 bb = reinterpret_cast<const f32x4*>(mln_b)[tid];
    bf16x4 o;
    #pragma unroll
    for (int j = 0; j < 4; ++j)
        o[j] = (bf16_t)fmaxf((v[j] - mean) * rstd * g[j] + bb[j], 0.f);
    reinterpret_cast<bf16x4*>(zbf)[b * 256 + tid] = o;
}

// ---------------------------------------------------------------------------
// Kernel 6: logits = zbf @ mW2.T + mb2  (MFMA). grid 2 (seg-halves).
// ---------------------------------------------------------------------------
__global__ __launch_bounds__(512) void k_logits(const u16* __restrict__ zbf,
                                                const u16* __restrict__ mW2f,
                                                const float* __restrict__ mb2,
                                                float* __restrict__ logits) {
    __shared__ __align__(16) u16 alds[128 * 256];   // 64KB
    const int tid  = threadIdx.x;
    const int lane = tid & 63;
    const int w    = tid >> 6;
    const int wm   = w >> 2;
    const int wn   = w & 3;
    const int l15  = lane & 15;
    const int g4   = lane >> 4;
    const int sh_  = blockIdx.x;        // 0..1

    f32x4 acc[4][4];
    #pragma unroll
    for (int m = 0; m < 4; ++m)
        #pragma unroll
        for (int t = 0; t < 4; ++t)
            acc[m][t] = (f32x4){0.f, 0.f, 0.f, 0.f};

    const uint4* srcU = reinterpret_cast<const uint4*>(zbf);
    const bf16x8* __restrict__ WB = reinterpret_cast<const bf16x8*>(mW2f);

    for (int kc = 0; kc < 4; ++kc) {
        __syncthreads();
        #pragma unroll
        for (int uu = 0; uu < 8; ++uu) {
            int lu = uu * 512 + tid;    // 0..4095
            int r  = lu >> 5;           // 0..127
            int u  = lu & 31;
            uint4 val = srcU[(size_t)(sh_ * 128 + r) * 128 + kc * 32 + u];
            int phys = r * 256 + ((u ^ (r & 7)) << 3);
            *reinterpret_cast<uint4*>(&alds[phys]) = val;
        }
        __syncthreads();
        #pragma unroll
        for (int ksl = 0; ksl < 8; ++ksl) {
            bf16x8 b[4];
            #pragma unroll
            for (int t = 0; t < 4; ++t)
                b[t] = WB[((kc * 8 + ksl) * 16 + wn * 4 + t) * 64 + lane];
            bf16x8 a[4];
            #pragma unroll
            for (int m = 0; m < 4; ++m) {
                int r = wm * 64 + m * 16 + l15;
                int u = ksl * 4 + g4;
                a[m] = *reinterpret_cast<const bf16x8*>(&alds[r * 256 + ((u ^ (r & 7)) << 3)]);
            }
            #pragma unroll
            for (int m = 0; m < 4; ++m)
                #pragma unroll
                for (int t = 0; t < 4; ++t)
                    acc[m][t] = __builtin_amdgcn_mfma_f32_16x16x32_bf16(a[m], b[t], acc[m][t], 0, 0, 0);
        }
    }

    #pragma unroll
    for (int t = 0; t < 4; ++t) {
        int col = (wn * 4 + t) * 16 + l15;   // 0..255
        if (col < OUTF) {
            float bias = mb2[col];
            #pragma unroll
            for (int m = 0; m < 4; ++m)
                #pragma unroll
                for (int j = 0; j < 4; ++j) {
                    int seg = sh_ * 128 + wm * 64 + m * 16 + g4 * 4 + j;
                    logits[(size_t)seg * OUTF + col] = acc[m][t][j] + bias;
                }
        }
    }
}

// ---------------------------------------------------------------------------
extern "C" void kernel_launch(void* const* d_in, const int* in_sizes, int n_in,
                              void* d_out, int out_size, void* d_ws, size_t ws_size,
                              hipStream_t stream) {
    const float* x     = (const float*)d_in[0];
    const int*   ids   = (const int*)  d_in[1];
    const float* gW1   = (const float*)d_in[2];
    const float* gb1   = (const float*)d_in[3];
    const float* gln_g = (const float*)d_in[4];
    const float* gln_b = (const float*)d_in[5];
    const float* gW2   = (const float*)d_in[6];
    const float* gb2   = (const float*)d_in[7];
    const float* pn_g  = (const float*)d_in[8];
    const float* pn_b  = (const float*)d_in[9];
    const float* mW1   = (const float*)d_in[10];
    const float* mb1   = (const float*)d_in[11];
    const float* mln_g = (const float*)d_in[12];
    const float* mln_b = (const float*)d_in[13];
    const float* mW2   = (const float*)d_in[14];
    const float* mb2   = (const float*)d_in[15];
    float* logits = (float*)d_out;

    char* ws = (char*)d_ws;
    const size_t MB = 1 << 20;
    u16*   Wf      = (u16*)  (ws);                  // 1 MB
    u16*   mW1f    = (u16*)  (ws + 1 * MB);         // 1 MB
    u16*   mW2f    = (u16*)  (ws + 2 * MB);         // 512 KB
    float* gate    = (float*)(ws + 5 * MB / 2);     // 400 KB
    float* pooledp = (float*)(ws + 4 * MB);         // PQ*256*512*4 = 4 MB
    u16*   outbf   = (u16*)  (ws + 8 * MB);         // 256 KB
    float* y       = (float*)(ws + 9 * MB);         // 1 MB
    u16*   zbf     = (u16*)  (ws + 10 * MB);        // 512 KB

    hipLaunchKernelGGL(k_conv, dim3(640), dim3(256), 0, stream,
                       gW1, mW1, mW2, Wf, mW1f, mW2f);
    hipLaunchKernelGGL(k_gate, dim3(NG), dim3(512), 0, stream,
                       x, Wf, gb1, gln_g, gln_b, gW2, gb2, gate);
    hipLaunchKernelGGL(k_poolseg, dim3(NSEG, PQ), dim3(512), 0, stream,
                       ids, gate, x, pooledp);
    hipLaunchKernelGGL(k_pln, dim3(NSEG), dim3(128), 0, stream,
                       pooledp, pn_g, pn_b, outbf);
    hipLaunchKernelGGL(k_heady, dim3(4, 2), dim3(512), 0, stream,
                       outbf, mW1f, mb1, y);
    hipLaunchKernelGGL(k_headz, dim3(NSEG), dim3(256), 0, stream,
                       y, mln_g, mln_b, zbf);
    hipLaunchKernelGGL(k_logits, dim3(2), dim3(512), 0, stream,
                       zbf, mW2f, mb2, logits);
}